// Round 4
// baseline (144.894 us; speedup 1.0000x reference)
//
#include <hip/hip_runtime.h>
#include <math.h>

#define Bn 32
#define Nn 2000
#define En 32000
#define Vn 100000
#define Dn 128
#define Rn 39
#define Kn 8

#define SUBS 8
#define NPS (Nn / SUBS)   // 250 nodes per sub-block
#define NPAIR (Nn / 2)    // 1000 node pairs per graph
#define EQ (En / 4)       // 8000 edge-quads per graph
#define NR (NPS * Rn)     // 9750 LDS cells per sub-block
#define NRT (Nn * Rn)     // 78000 cells in a full per-graph count table
#define NRS 78080         // padded (16B-divisible) stride of per-graph count table
#define GBLK 16           // gather blocks per graph
#define WSLOT (GBLK * 8)  // 128 wave-slots per graph (8 waves/block)

// Workspace layout (no aliasing):
//   [ 0)          : cntg    uint8[B*NRS]         =  2,498,560   ([b][dst*39+et] counts)
//   [ 2,498,560)  : a       float[B*N*K]         =  2,048,000
//   [ 4,546,560)  : partial float[B*9*GBLK*128]  =  2,359,296   ([b][k][blk][d])
//
// R19 = R18 (142.1us) with the two per-edge latency adders removed and one
// dispatch eliminated:
//   - K2 preloads the FULL 78KB per-graph count table into LDS (coalesced
//     int4 from same-XCD L2) + a 256-entry IEEE 1/c LUT. Inner loop is
//     ds_read_u8 -> ds_read(lut) -> ds_atomic: no per-edge L2 gather, no
//     per-edge divide (R18 regression root-caused to these).
//   - K4+K5 fused into finish_kernel (32 blocks x 512 thr, no fences/election
//     -- R16 showed election fences cost more than a boundary saves).
//   4 dispatches total. Tests the fixed-dispatch-cost hypothesis cleanly.
// blockIdx.x = graph everywhere -> XCD affinity (R2 evidence: 9x fetch cut).

// K1: count by dst-range. 8 blocks/graph. Fused mad-filter:
// y = dst*39+et - sub*9750; in-range iff (unsigned)y < 9750.
__global__ __launch_bounds__(1024) void count_kernel(const int* __restrict__ edge_index,
                                                     const int* __restrict__ edge_type,
                                                     unsigned char* __restrict__ cntg) {
    int b = blockIdx.x, sub = blockIdx.y;
    int base = sub * NR;
    __shared__ int loc[NR];                       // 39 KB
    for (int i = threadIdx.x; i < NR; i += 1024) loc[i] = 0;
    __syncthreads();
    const int4* dst4 = (const int4*)(edge_index + (b * 2 + 1) * En);
    const int4* et4  = (const int4*)(edge_type + b * En);
    for (int q = threadIdx.x; q < EQ; q += 1024) {
        int4 d = dst4[q]; int4 t = et4[q]; int y;
        y = d.x * Rn + t.x - base; if ((unsigned)y < NR) atomicAdd(&loc[y], 1);
        y = d.y * Rn + t.y - base; if ((unsigned)y < NR) atomicAdd(&loc[y], 1);
        y = d.z * Rn + t.z - base; if ((unsigned)y < NR) atomicAdd(&loc[y], 1);
        y = d.w * Rn + t.w - base; if ((unsigned)y < NR) atomicAdd(&loc[y], 1);
    }
    __syncthreads();
    // coalesced byte dump (counts fit uint8: E/(N*R) ~ 0.41 expected/cell)
    unsigned char* cg = cntg + (size_t)b * NRS + base;
    for (int i = threadIdx.x; i < NR; i += 1024) {
        int c = loc[i];
        cg[i] = (unsigned char)(c > 255 ? 255 : c);
    }
}

// K2: 8 blocks/graph own src-ranges. Preload full count table (78KB) + 1/c
// LUT into LDS; stream src/dst/et; per edge: LDS byte read -> LUT read ->
// ONE LDS atomic into s[src*39+t] (stride 39, coprime to 32 banks); then
// a[n][k] = s @ comp.
__global__ __launch_bounds__(1024) void a_kernel(const int* __restrict__ edge_index,
                                                 const int* __restrict__ edge_type,
                                                 const unsigned char* __restrict__ cntg,
                                                 const float* __restrict__ comp,
                                                 float* __restrict__ a) {
    int b = blockIdx.x, sub = blockIdx.y;
    int base = sub * NR;
    __shared__ float s[NR];                                        // 39.0 KB
    __shared__ unsigned char cnt_l[NRT] __attribute__((aligned(16))); // 78.0 KB
    __shared__ float lut[256];                                     //  1.0 KB
    __shared__ float comp_l[Rn * Kn];                              //  1.2 KB
    for (int i = threadIdx.x; i < NR; i += 1024) s[i] = 0.0f;
    // coalesced int4 preload of the count table (written by K1 on same XCD)
    {
        const int4* src = (const int4*)(cntg + (size_t)b * NRS);
        int4* dst = (int4*)cnt_l;
        for (int i = threadIdx.x; i < NRT / 16; i += 1024) dst[i] = src[i];
    }
    if (threadIdx.x < 256) lut[threadIdx.x] = 1.0f / (float)threadIdx.x; // [0]=inf, unused
    if (threadIdx.x < Rn * Kn) comp_l[threadIdx.x] = comp[threadIdx.x];
    __syncthreads();
    const int4* src4 = (const int4*)(edge_index + (b * 2 + 0) * En);
    const int4* dst4 = (const int4*)(edge_index + (b * 2 + 1) * En);
    const int4* et4  = (const int4*)(edge_type + b * En);
    for (int q = threadIdx.x; q < EQ; q += 1024) {
        int4 sv = src4[q]; int4 dv = dst4[q]; int4 tv = et4[q]; int y;
        y = sv.x * Rn + tv.x - base;
        if ((unsigned)y < NR) atomicAdd(&s[y], lut[cnt_l[dv.x * Rn + tv.x]]);
        y = sv.y * Rn + tv.y - base;
        if ((unsigned)y < NR) atomicAdd(&s[y], lut[cnt_l[dv.y * Rn + tv.y]]);
        y = sv.z * Rn + tv.z - base;
        if ((unsigned)y < NR) atomicAdd(&s[y], lut[cnt_l[dv.z * Rn + tv.z]]);
        y = sv.w * Rn + tv.w - base;
        if ((unsigned)y < NR) atomicAdd(&s[y], lut[cnt_l[dv.w * Rn + tv.w]]);
    }
    __syncthreads();
    float* g = a + ((size_t)b * Nn + sub * NPS) * Kn;
    for (int i = threadIdx.x; i < NPS * Kn; i += 1024) {   // 2000 outputs
        int n = i >> 3, k = i & 7;
        float acc = 0.0f;
        const float* srow = &s[n * Rn];
        for (int t = 0; t < Rn; t++) acc += srow[t] * comp_l[t * Kn + k];
        g[i] = acc;
    }
}

// K3: paired gather, 8 waves/block, 16 blocks/graph (unchanged from R17).
__global__ __launch_bounds__(512, 4) void gather_kernel(const int* __restrict__ node_ids,
                                                        const float* __restrict__ emb,
                                                        const float* __restrict__ a,
                                                        float* __restrict__ partial) {
    int b = blockIdx.x;
    int lane = threadIdx.x & 63, wv = threadIdx.x >> 6;
    int Wl = blockIdx.y * 8 + wv;                 // wave-slot in [0, WSLOT)
    int half = lane >> 5;                         // 0: even node, 1: odd node
    int dl = lane & 31;                           // float4 slot: d = 4*dl..4*dl+3
    __shared__ float red[8][9][Dn];               // 36.9 KB
    float4 acc[9];
#pragma unroll
    for (int k = 0; k < 9; k++) acc[k] = make_float4(0.f, 0.f, 0.f, 0.f);
    const int*   nb = node_ids + b * Nn;
    const float* ab = a + (size_t)b * Nn * Kn;
#pragma unroll
    for (int i0 = 0; i0 < 8; i0 += 4) {           // two batch-4 rounds
        bool   has[4];
        int    node[4];
        float4 v[4];
        float4 a0[4], a1[4];
#pragma unroll
        for (int i = 0; i < 4; i++) {
            int p = Wl + (i0 + i) * WSLOT;
            has[i] = p < NPAIR;
            node[i] = (has[i] ? 2 * p : 0) + half;
        }
#pragma unroll
        for (int i = 0; i < 4; i++) {             // 4 batched 1KB row loads
            int nid = nb[node[i]];
            v[i] = has[i] ? ((const float4*)(emb + (size_t)nid * Dn))[dl]
                          : make_float4(0.f, 0.f, 0.f, 0.f);
            const float4* ar = (const float4*)(ab + (size_t)node[i] * Kn);
            a0[i] = ar[0]; a1[i] = ar[1];
        }
#pragma unroll
        for (int i = 0; i < 4; i++) {
            float w[9] = {a0[i].x, a0[i].y, a0[i].z, a0[i].w,
                          a1[i].x, a1[i].y, a1[i].z, a1[i].w, 1.0f};
#pragma unroll
            for (int k = 0; k < 9; k++) {
                acc[k].x += w[k] * v[i].x;
                acc[k].y += w[k] * v[i].y;
                acc[k].z += w[k] * v[i].z;
                acc[k].w += w[k] * v[i].w;
            }
        }
    }
    // merge odd-node half into even half (same d-range)
#pragma unroll
    for (int k = 0; k < 9; k++) {
        acc[k].x += __shfl_down(acc[k].x, 32, 64);
        acc[k].y += __shfl_down(acc[k].y, 32, 64);
        acc[k].z += __shfl_down(acc[k].z, 32, 64);
        acc[k].w += __shfl_down(acc[k].w, 32, 64);
    }
    if (half == 0) {
#pragma unroll
        for (int k = 0; k < 9; k++)
            ((float4*)red[wv][k])[dl] = acc[k];
    }
    __syncthreads();
    // cross-wave reduce 8->1: threads 0..287 each own one (k, d4) float4 slot
    int slot = threadIdx.x;
    if (slot < 9 * (Dn / 4)) {
        int k = slot >> 5, d4 = slot & 31;
        float4 t = make_float4(0.f, 0.f, 0.f, 0.f);
#pragma unroll
        for (int w = 0; w < 8; w++) {
            float4 v = ((const float4*)red[w][k])[d4];
            t.x += v.x; t.y += v.y; t.z += v.z; t.w += v.w;
        }
        float4* gp = (float4*)(partial + (((size_t)b * 9 + k) * GBLK + blockIdx.y) * Dn);
        gp[d4] = t;
    }
}

// K4+K5 fused: one block per graph. Phase 1: reduce 16 partial slabs ->
// ts[9][128] in LDS. Phase 2: 9 matvecs, float4 along d, 16 j-groups x 32
// d4-slots; reduce j-groups through LDS; bias + L2-normalize inline.
__global__ __launch_bounds__(512) void finish_kernel(const float* __restrict__ partial,
                                                     const float* __restrict__ root,
                                                     const float* __restrict__ bases,
                                                     const float* __restrict__ bias,
                                                     float* __restrict__ out) {
    int b = blockIdx.x, tid = threadIdx.x;
    __shared__ float ts[9][Dn];                   // 4.6 KB
    __shared__ float4 red4[16][Dn / 4];           // 8 KB
    __shared__ float ssr[8];
    // phase 1: ts[k][d] = sum over 16 gather-block slabs (coalesced along d)
    for (int slot = tid; slot < 9 * Dn; slot += 512) {
        int k = slot >> 7, d = slot & 127;
        const float* pp = partial + (((size_t)b * 9 + k) * GBLK) * Dn + d;
        float t = 0.0f;
#pragma unroll
        for (int c = 0; c < GBLK; c++) t += pp[c * Dn];
        ts[k][d] = t;
    }
    __syncthreads();
    // phase 2: acc[d4] = sum_m sum_j ts[m][j] * M_m[j][4*d4..4*d4+3]
    int d4 = tid & 31, jg = tid >> 5;             // 16 j-groups of 8 rows
    float4 acc = make_float4(0.f, 0.f, 0.f, 0.f);
    for (int m = 0; m < 9; m++) {
        const float4* M4 = (const float4*)((m == 8) ? root : bases + (size_t)m * Dn * Dn);
        const float* tsm = ts[m];
#pragma unroll
        for (int jj = 0; jj < 8; jj++) {
            int j = jg * 8 + jj;
            float w = tsm[j];
            float4 mv = M4[j * 32 + d4];
            acc.x += w * mv.x; acc.y += w * mv.y; acc.z += w * mv.z; acc.w += w * mv.w;
        }
    }
    red4[jg][d4] = acc;
    __syncthreads();
    // g[d] for d = tid&127 (jg-duplicated x4, bit-identical)
    const float* redf = (const float*)red4;       // [16][128]
    int d = tid & 127;
    float g = (float)Nn * bias[d];
#pragma unroll
    for (int w = 0; w < 16; w++) g += redf[w * Dn + d];
    // sum of squares: 8 waves cover d=0..127 four times -> x0.25 (exact)
    float ss = g * g;
#pragma unroll
    for (int off = 32; off > 0; off >>= 1) ss += __shfl_down(ss, off, 64);
    if ((tid & 63) == 0) ssr[tid >> 6] = ss;
    __syncthreads();
    float tot = (ssr[0] + ssr[1] + ssr[2] + ssr[3] +
                 ssr[4] + ssr[5] + ssr[6] + ssr[7]) * 0.25f;
    float nrm = sqrtf(tot);
    if (tid < Dn) out[b * Dn + tid] = g / fmaxf(nrm, 1e-5f);
}

extern "C" void kernel_launch(void* const* d_in, const int* in_sizes, int n_in,
                              void* d_out, int out_size, void* d_ws, size_t ws_size,
                              hipStream_t stream) {
    const int*   node_ids   = (const int*)d_in[0];
    const int*   edge_index = (const int*)d_in[1];
    const int*   edge_type  = (const int*)d_in[2];
    const float* embedding  = (const float*)d_in[3];
    const float* bases      = (const float*)d_in[4];
    const float* comp       = (const float*)d_in[5];
    const float* root       = (const float*)d_in[6];
    const float* bias       = (const float*)d_in[7];
    float*       out        = (float*)d_out;

    char* w = (char*)d_ws;
    unsigned char* cntg    = (unsigned char*)(w + 0);
    float*         a       = (float*)(w + 2498560);
    float*         partial = (float*)(w + 4546560);

    count_kernel <<<dim3(Bn, SUBS), 1024, 0, stream>>>(edge_index, edge_type, cntg);
    a_kernel     <<<dim3(Bn, SUBS), 1024, 0, stream>>>(edge_index, edge_type, cntg, comp, a);
    gather_kernel<<<dim3(Bn, GBLK), 512,  0, stream>>>(node_ids, embedding, a, partial);
    finish_kernel<<<Bn, 512, 0, stream>>>(partial, root, bases, bias, out);
}